// Round 1
// baseline (320.717 us; speedup 1.0000x reference)
//
#include <hip/hip_runtime.h>
#include <hip/hip_bf16.h>

// y[b,c,h,w] = x[b,c,h,w] + 0.2 * sum of 8 in-bounds neighbors (zero-padded).
// fp32, B=8 C=16 H=1024 W=1024. Memory-bound stencil.
//
// Layout is fully contiguous, so a flat "row" index r in [0, B*C*H) maps to
// offset r*W; h = r % H decides whether the row above/below exists (rows of
// different (b,c) images never mix because h==0 / h==H-1 cut the stencil).

#define ALPHA 0.2f

__device__ __forceinline__ void load6(const float* __restrict__ p, int w, int W,
                                      float v[6]) {
    // v[0] = p[w-1] (0 if OOB), v[1..4] = p[w..w+3], v[5] = p[w+4] (0 if OOB)
    const float4 c = *reinterpret_cast<const float4*>(p + w);
    v[0] = (w > 0) ? p[w - 1] : 0.0f;
    v[1] = c.x; v[2] = c.y; v[3] = c.z; v[4] = c.w;
    v[5] = (w + 4 < W) ? p[w + 4] : 0.0f;
}

__global__ __launch_bounds__(256)
void contamination_kernel(const float* __restrict__ x, float* __restrict__ y,
                          int H, int W) {
    const int row = blockIdx.x;               // 0 .. B*C*H-1
    const int h = row & (H - 1);              // H is a power of two (1024)
    const size_t base = (size_t)row * (size_t)W;
    const int w = threadIdx.x * 4;            // 256 threads * 4 floats = W

    const float* __restrict__ mrow = x + base;

    float tv[6] = {0.f, 0.f, 0.f, 0.f, 0.f, 0.f};
    float bv[6] = {0.f, 0.f, 0.f, 0.f, 0.f, 0.f};
    float mv[6];

    load6(mrow, w, W, mv);
    if (h > 0)      load6(mrow - W, w, W, tv);
    if (h < H - 1)  load6(mrow + W, w, W, bv);

    float4 out;
    float* o = reinterpret_cast<float*>(&out);
#pragma unroll
    for (int j = 0; j < 4; ++j) {
        const float nb = tv[j] + tv[j + 1] + tv[j + 2] +
                         bv[j] + bv[j + 1] + bv[j + 2] +
                         mv[j] + mv[j + 2];
        o[j] = mv[j + 1] + ALPHA * nb;
    }

    *reinterpret_cast<float4*>(y + base + w) = out;
}

extern "C" void kernel_launch(void* const* d_in, const int* in_sizes, int n_in,
                              void* d_out, int out_size, void* d_ws, size_t ws_size,
                              hipStream_t stream) {
    const float* x = (const float*)d_in[0];
    float* y = (float*)d_out;

    const int W = 1024;
    const int H = 1024;
    const int n = in_sizes[0];            // B*C*H*W = 134217728
    const int rows = n / W;               // B*C*H = 131072

    dim3 grid(rows);
    dim3 block(W / 4);                    // 256 threads, one float4 each
    contamination_kernel<<<grid, block, 0, stream>>>(x, y, H, W);
}

// Round 3
// 203.714 us; speedup vs baseline: 1.5744x; 1.5744x over previous
//
#include <hip/hip_runtime.h>
#include <hip/hip_bf16.h>

// y = x + 0.2 * (8-neighbor sum), fp32, (8,16,1024,1024), zero-padded edges.
//
// R2b: register-rolling vertical tiling (R2 with native ext_vector_type for
// the nontemporal store — HIP float4 is a class and rejected by the builtin).
// Each block owns a 16-row x 1024-col tile of one image; 256 threads each
// produce a float4-wide column strip. Rows load ONCE into a rolling 3-row
// register window. Read amplification (ROWS+2)/ROWS = 1.125x. Output streamed
// with nontemporal stores to keep reusable input rows in L2.

#define ALPHA 0.2f
#define ROWS 16

typedef float f4 __attribute__((ext_vector_type(4)));

__device__ __forceinline__ void load6(const float* __restrict__ p, int w, int W,
                                      float v[6]) {
    const f4 c = *reinterpret_cast<const f4*>(p + w);
    v[0] = (w > 0) ? p[w - 1] : 0.0f;
    v[1] = c.x; v[2] = c.y; v[3] = c.z; v[4] = c.w;
    v[5] = (w + 4 < W) ? p[w + 4] : 0.0f;
}

__global__ __launch_bounds__(256)
void contamination_kernel(const float* __restrict__ x, float* __restrict__ y,
                          int H, int W) {
    const int tilesPerImg = H / ROWS;                  // 64
    const int tile = blockIdx.x;
    const int img  = tile / tilesPerImg;
    const int h0   = (tile - img * tilesPerImg) * ROWS;
    const size_t base = ((size_t)img * H + (size_t)h0) * W;
    const int w = threadIdx.x * 4;

    const float* __restrict__ row = x + base;          // row h0
    float* __restrict__ orow = y + base;

    float t[6], m[6], b[6];
#pragma unroll
    for (int j = 0; j < 6; ++j) t[j] = 0.0f;

    if (h0 > 0) load6(row - W, w, W, t);               // halo above
    load6(row, w, W, m);

#pragma unroll
    for (int i = 0; i < ROWS; ++i) {
        if (h0 + i + 1 < H) {
            load6(row + W, w, W, b);                   // next row (halo below on last tile)
        } else {
#pragma unroll
            for (int j = 0; j < 6; ++j) b[j] = 0.0f;
        }

        f4 o;
#pragma unroll
        for (int j = 0; j < 4; ++j) {
            const float nb = t[j] + t[j + 1] + t[j + 2] +
                             b[j] + b[j + 1] + b[j + 2] +
                             m[j] + m[j + 2];
            o[j] = m[j + 1] + ALPHA * nb;
        }
        __builtin_nontemporal_store(o, reinterpret_cast<f4*>(orow + w));

        // rotate the register window (indices are compile-time after unroll)
#pragma unroll
        for (int j = 0; j < 6; ++j) { t[j] = m[j]; m[j] = b[j]; }
        row += W; orow += W;
    }
}

extern "C" void kernel_launch(void* const* d_in, const int* in_sizes, int n_in,
                              void* d_out, int out_size, void* d_ws, size_t ws_size,
                              hipStream_t stream) {
    const float* x = (const float*)d_in[0];
    float* y = (float*)d_out;

    const int W = 1024;
    const int H = 1024;
    const int n = in_sizes[0];                 // B*C*H*W
    const int blocks = n / (W * ROWS);         // 8192

    contamination_kernel<<<dim3(blocks), dim3(W / 4), 0, stream>>>(x, y, H, W);
}